// Round 1
// baseline (317.645 us; speedup 1.0000x reference)
//
#include <hip/hip_runtime.h>

#define H_ 128
#define W_ 160
#define HW_ (H_ * W_)
#define EMPTY_KEY 0xFFFFFFFFu

__device__ __forceinline__ unsigned mix32(unsigned h) {
    // murmur3 fmix32
    h ^= h >> 16; h *= 0x85ebca6bu;
    h ^= h >> 13; h *= 0xc2b2ae35u;
    h ^= h >> 16;
    return h;
}

// One thread per event. blockIdx.y = batch.
__global__ __launch_bounds__(256) void iwe_scatter(
    const float4* __restrict__ ev,      // (B, N, 4): ts, y, x, p
    const float* __restrict__ flow,     // (B, 2, HW): ch0 = fx, ch1 = fy
    float* __restrict__ out,            // (B, 2, HW): ch0 = pos, ch1 = neg (accumulates)
    unsigned* __restrict__ contrib,     // (B, 2, HW) distinct-source counts
    unsigned* __restrict__ table,       // B hash tables of (mask+1) entries each
    int N, unsigned mask)
{
    int i = blockIdx.x * blockDim.x + threadIdx.x;
    int b = blockIdx.y;
    if (i >= N) return;

    float4 e = ev[(size_t)b * N + i];
    float ts = e.x, yf = e.y, xf = e.z, p = e.w;

    int src = (int)yf * W_ + (int)xf;                 // y,x are exact small ints
    const float* fl = flow + (size_t)b * 2 * HW_;
    float fx = fl[src];          // flow channel 0 (x)
    float fy = fl[HW_ + src];    // flow channel 1 (y)

    // Bit-exact numpy op order: y + ((1 - ts) * f) * 160, no FMA contraction.
    float dt = __fsub_rn(1.0f, ts);
    float wy = __fadd_rn(yf, __fmul_rn(__fmul_rn(dt, fy), 160.0f));
    float wx = __fadd_rn(xf, __fmul_rn(__fmul_rn(dt, fx), 160.0f));

    float ry = rintf(wy);   // round half to even, matches jnp.round/np.round
    float rx = rintf(wx);

    // Validity on the *rounded* floats (so -0.0 counts as valid, like the ref).
    if (!(ry >= 0.0f && ry < (float)H_ && rx >= 0.0f && rx < (float)W_)) return;

    int fw = (int)ry * W_ + (int)rx;
    int c = (p > 0.0f) ? 0 : 1;                       // out channel: 0=pos, 1=neg
    size_t oidx = ((size_t)b * 2 + c) * HW_ + fw;

    atomicAdd(&out[oidx], 1.0f);                      // weight * pol_mask is exactly 1

    // Dedup (pol, src, fw) via per-batch open-addressing hash set.
    unsigned key = ((unsigned)c << 30) | ((unsigned)src << 15) | (unsigned)fw; // < 2^31
    volatile unsigned* tb = (volatile unsigned*)(table + (size_t)b * (mask + 1u));
    unsigned h = mix32(key) & mask;
    for (unsigned probe = 0; probe <= mask; ++probe) {
        unsigned cur = tb[h];                          // cheap pre-read (stale-safe)
        if (cur == key) return;                        // duplicate
        if (cur == EMPTY_KEY) {
            unsigned prev = atomicCAS((unsigned*)&tb[h], EMPTY_KEY, key);
            if (prev == EMPTY_KEY) {                   // first occurrence of triple
                atomicAdd(&contrib[oidx], 1u);
                return;
            }
            if (prev == key) return;                   // raced duplicate
            // else another key won this slot -> keep probing
        }
        h = (h + 1u) & mask;
    }
}

__global__ __launch_bounds__(256) void iwe_div(
    float* __restrict__ out, const unsigned* __restrict__ contrib, int n)
{
    int i = blockIdx.x * blockDim.x + threadIdx.x;
    if (i < n) {
        unsigned c = contrib[i];
        if (c > 0u) out[i] = __fdiv_rn(out[i], (float)c);
    }
}

extern "C" void kernel_launch(void* const* d_in, const int* in_sizes, int n_in,
                              void* d_out, int out_size, void* d_ws, size_t ws_size,
                              hipStream_t stream) {
    const float*  flow = (const float*)d_in[0];
    const float4* ev   = (const float4*)d_in[1];
    // d_in[2] (pol_mask) is redundant with event_list's p column — not read.

    int B = in_sizes[0] / (2 * HW_);          // = 4
    int N = in_sizes[1] / (B * 4);            // = 1,000,000

    // Workspace layout: [contrib: out_size u32][hash tables: B * cap u32]
    size_t contribBytes = (size_t)out_size * sizeof(unsigned);
    unsigned cap = 1u << 22;                  // 4M entries/batch -> load factor <= 0.25
    while (cap > (1u << 16) &&
           contribBytes + (size_t)B * cap * sizeof(unsigned) > ws_size)
        cap >>= 1;

    unsigned* contrib = (unsigned*)d_ws;
    unsigned* table   = (unsigned*)((char*)d_ws + contribBytes);

    hipMemsetAsync(d_out, 0, (size_t)out_size * sizeof(float), stream);
    hipMemsetAsync(contrib, 0, contribBytes, stream);
    hipMemsetAsync(table, 0xFF, (size_t)B * cap * sizeof(unsigned), stream);

    dim3 grid((N + 255) / 256, B);
    iwe_scatter<<<grid, 256, 0, stream>>>(ev, flow, (float*)d_out, contrib, table,
                                          N, cap - 1u);
    iwe_div<<<(out_size + 255) / 256, 256, 0, stream>>>((float*)d_out, contrib, out_size);
}